// Round 7
// baseline (106.464 us; speedup 1.0000x reference)
//
#include <hip/hip_runtime.h>
#include <hip/hip_bf16.h>

// ---------------------------------------------------------------------------
// Adalibi: out[n,0,h,p*N+c] = (inv_p[n]==c) * sqrt(exp(slope_h)) / sqrt(P)
//   N=2048, H=16, P=2, k=37. Output f32, 2048*16*4096 = 134,217,728 elems.
// Single fused kernel, LOW-OCCUPANCY variant: 512 blocks (2/CU), each block
// owns 4 consecutive n-slabs (4 x 256 KB = 1 MB contiguous):
//   1) redundant change-count on [1, n0] (order-independent == reference
//      cumsum) + 3-step serial window prefix  -> inv_p[n0..n0+3]
//   2) 256 nontemporal 16B stores per thread, nonzeros via compare/select.
// Rationale: rocclr fillBuffer hits 6.8 TB/s at ~3.4 waves/CU; our 32-wave/CU
// version ran at 5.4 TB/s. Fewer, longer write streams -> better DRAM locality.
// inv_p[n] = #{m in 1..n : ceil((t_m-u_p)/d_p) != ceil((t_{m-1}-u_p)/d_p)}
// ---------------------------------------------------------------------------

#define N_SEQ 2048
#define H_NUM 16
#define P_NUM 2
#define SLABS 4   // n-slabs per block

typedef float fx4 __attribute__((ext_vector_type(4)));  // nt-store-compatible

__device__ __forceinline__ int bin_idx(int kk, int m, float up, float dp) {
    // EXACT mirror of reference f32 arithmetic: ceil((t - u)/delta), t = kk+m
    return (int)ceilf(((float)(kk + m) - up) / dp);
}

__global__ __launch_bounds__(256) void fused_fill_kernel(
        const float* __restrict__ delta, const float* __restrict__ u,
        const int* __restrict__ kptr, fx4* __restrict__ out) {
    const int blk = blockIdx.x;          // 0..511
    const int tid = threadIdx.x;         // 0..255
    const int n0  = blk << 2;            // first n of this block's 4-slab window
    const int kk  = kptr[0];

    __shared__ int   s_cnt[P_NUM];
    __shared__ int   s_wpre[P_NUM][SLABS];
    __shared__ float sval[H_NUM];

    if (tid < P_NUM) s_cnt[tid] = 0;
    if (tid < H_NUM) {
        // val_h = sqrt(exp(2^(-(h+1)/2))) / sqrt(2) (matches reference f32 path)
        const float slope = exp2f(-0.5f * (float)(tid + 1));
        sval[tid] = sqrtf(expf(slope)) * 0.70710678118f;
    }
    if (tid >= 32 && tid < 32 + P_NUM) {
        // serial window prefix (3 flag evals) — one thread per p, separate wave
        const int p = tid - 32;
        const float dp = delta[p], up = u[p];
        int acc = 0;
        s_wpre[p][0] = 0;
        int prev = bin_idx(kk, n0, up, dp);
        for (int d = 1; d < SLABS; ++d) {
            int cur = bin_idx(kk, n0 + d, up, dp);
            acc += (cur != prev) ? 1 : 0;
            prev = cur;
            s_wpre[p][d] = acc;
        }
    }
    __syncthreads();

    // Count changes m in [1, n0] for p = tid>>7 (128 threads per p).
    {
        const int p = tid >> 7;
        const float dp = delta[p], up = u[p];
        int local = 0;
        for (int m = 1 + (tid & 127); m <= n0; m += 128) {
            int a = bin_idx(kk, m,     up, dp);
            int b = bin_idx(kk, m - 1, up, dp);
            local += (a != b) ? 1 : 0;
        }
        #pragma unroll
        for (int off = 32; off > 0; off >>= 1)
            local += __shfl_down(local, off, 64);
        if ((tid & 63) == 0) atomicAdd(&s_cnt[p], local);
    }
    __syncthreads();

    // Stream 4 consecutive slabs (1 MB contiguous per block).
    for (int d = 0; d < SLABS; ++d) {
        const int inv0 = s_cnt[0] + s_wpre[0][d];
        const int inv1 = s_cnt[1] + s_wpre[1][d];
        fx4* __restrict__ slab = out + (size_t)(n0 + d) * 16384u;

        #pragma unroll 4
        for (int j = 0; j < 64; ++j) {
            const int pos  = tid + (j << 8);        // float4 index in slab
            const int h    = pos >> 10;             // 1024 float4 per row
            const float v  = sval[h];               // wave-uniform LDS broadcast
            const int col0 = (pos & 1023) << 2;     // float column 0..4092
            const int tgt  = (col0 & 2048) ? inv1 : inv0;   // p = col0>>11
            const int c    = col0 & 2047;

            fx4 o;
            o.x = (tgt == c)     ? v : 0.0f;
            o.y = (tgt == c + 1) ? v : 0.0f;
            o.z = (tgt == c + 2) ? v : 0.0f;
            o.w = (tgt == c + 3) ? v : 0.0f;
            __builtin_nontemporal_store(o, &slab[pos]);
        }
    }
}

extern "C" void kernel_launch(void* const* d_in, const int* in_sizes, int n_in,
                              void* d_out, int out_size, void* d_ws, size_t ws_size,
                              hipStream_t stream) {
    // inputs: [0]=x (unused, dtype only), [1]=delta (P,1) f32, [2]=u (P,1) f32,
    //         [3]=seq_len (int), [4]=k (int)
    const float* delta = (const float*)d_in[1];
    const float* u     = (const float*)d_in[2];
    const int*   kptr  = (const int*)d_in[4];

    fused_fill_kernel<<<N_SEQ / SLABS, 256, 0, stream>>>(delta, u, kptr, (fx4*)d_out);
}